// Round 1
// baseline (27.211 us; speedup 1.0000x reference)
//
#include <hip/hip_runtime.h>

// TransMatch: 2-hop knowledge-graph aggregation + linear scorer.
// BS=1024, D=64, S=16, HOPS=2, AGG=1.0, N_REL=16.
// Key trick: relation_emb is 16x64 -> inner masked sums of relation vectors
// become 16-bin histograms contracted against register-resident R.

#define BSZ 1024
#define DIM 64
#define NS 16
#define NREL 16

__global__ __launch_bounds__(256, 4) void transmatch_kernel(
    const int* __restrict__ relations,      // (BS,)
    const int* __restrict__ entity_pairs,   // (BS,2)
    const int* __restrict__ train_edges,    // (BS,)
    const int* __restrict__ entity2edges,   // (N_ENT,16)
    const int* __restrict__ edge2entities,  // (N_EDGE,2)
    const int* __restrict__ edge2relation,  // (N_EDGE,)
    const float* __restrict__ relation_emb, // (16,64)
    const float* __restrict__ entity_emb,   // (N_ENT,64)
    const float* __restrict__ scorer_w,     // (64,1)
    const float* __restrict__ scorer_b,     // (1,)
    float* __restrict__ out)                // (BS,)
{
    __shared__ float Rl[NREL * DIM];        // 4 KB relation table
    __shared__ float nb1[64 * DIM];         // 16 KB: ent1[n] + agg2[n]
    __shared__ int   edges1_l[32];
    __shared__ int   rel1_l[32];
    __shared__ int   mask0_l[32];
    __shared__ int   node_l[64];
    __shared__ unsigned int hist_l[64][4];  // 16 bytes = 16 bins of u8
    __shared__ int   cnt1_l[64];
    __shared__ float sum1[2][DIM];          // masked sum of original ev1
    __shared__ float sum1p[2][DIM];         // masked sum of updated ev1'
    __shared__ float ent0[2][DIM];

    const int b    = blockIdx.x;
    const int t    = threadIdx.x;
    const int lane = t & 63;
    const int wave = t >> 6;

    const int te = train_edges[b];

    // ---- load relation_emb into LDS (1024 floats / 256 threads) ----
    #pragma unroll
    for (int i = 0; i < 4; ++i)
        Rl[t + i * 256] = relation_emb[t + i * 256];

    // ---- step 1: first-hop edges (32 threads), j = p*16 + s ----
    if (t < 32) {
        const int p    = t >> 4;
        const int e    = entity_pairs[b * 2 + p];
        const int edge = entity2edges[e * NS + (t & 15)];
        edges1_l[t] = edge;
        rel1_l[t]   = edge2relation[edge];
        mask0_l[t]  = (edge != te) ? 1 : 0;
    }
    __syncthreads();

    // ---- step 2: second-hop nodes (64 threads), n = j*2 + p2 ----
    if (t < 64) {
        node_l[t] = edge2entities[edges1_l[t >> 1] * 2 + (t & 1)];
    }
    __syncthreads();

    // ---- step 3: per-node relation histograms (all 256 threads) ----
    // thread t handles node n = t>>2, s-quad sq = t&3 (4 edges each).
    {
        const int n  = t >> 2;
        const int sq = t & 3;
        const int node = node_l[n];
        const int4 ed = reinterpret_cast<const int4*>(entity2edges)[node * 4 + sq];
        int ee[4] = { ed.x, ed.y, ed.z, ed.w };
        int rr[4];
        #pragma unroll
        for (int k = 0; k < 4; ++k) rr[k] = edge2relation[ee[k]];

        unsigned long long lo = 0ull, hi = 0ull; // 16 bins x u8 (rel 0..7 / 8..15)
        int cnt = 0;
        #pragma unroll
        for (int k = 0; k < 4; ++k) {
            if (ee[k] != te) {
                const unsigned long long bit = 1ull << ((rr[k] & 7) * 8);
                if (rr[k] < 8) lo += bit; else hi += bit;
                cnt++;
            }
        }
        // combine the 4 threads of this n (same wave, adjacent lanes)
        lo  += __shfl_xor(lo, 1);  lo  += __shfl_xor(lo, 2);
        hi  += __shfl_xor(hi, 1);  hi  += __shfl_xor(hi, 2);
        cnt += __shfl_xor(cnt, 1); cnt += __shfl_xor(cnt, 2);
        if (sq == 0) {
            hist_l[n][0] = (unsigned int)lo;
            hist_l[n][1] = (unsigned int)(lo >> 32);
            hist_l[n][2] = (unsigned int)hi;
            hist_l[n][3] = (unsigned int)(hi >> 32);
            cnt1_l[n]    = cnt;
        }
    }
    __syncthreads();

    // ---- phase B: nb1[n] = entity_emb[node] + (hist . R)/max(cnt,1) ----
    // lane = dim d; wave w owns n in [16w, 16w+16). R in 16 VGPRs (static idx).
    {
        float Rreg[NREL];
        #pragma unroll
        for (int r = 0; r < NREL; ++r) Rreg[r] = Rl[r * DIM + lane];

        for (int ni = 0; ni < 16; ++ni) {
            const int n = wave * 16 + ni;
            const float ent = entity_emb[(long long)node_l[n] * DIM + lane];
            const unsigned int h0 = hist_l[n][0];
            const unsigned int h1 = hist_l[n][1];
            const unsigned int h2 = hist_l[n][2];
            const unsigned int h3 = hist_l[n][3];
            float acc = 0.0f;
            #pragma unroll
            for (int r = 0; r < NREL; ++r) {
                const unsigned int word = (r < 4) ? h0 : (r < 8) ? h1 : (r < 12) ? h2 : h3;
                const unsigned int c = (word >> ((r & 3) * 8)) & 0xffu;
                acc = fmaf((float)c, Rreg[r], acc);
            }
            const float inv = 1.0f / (float)max(cnt1_l[n], 1);
            nb1[n * DIM + lane] = fmaf(acc, inv, ent);
        }
    }
    __syncthreads();

    // ---- phase C ----
    if (wave < 2) {
        // masked sum of UPDATED ev1'[j] = R[rel1[j]] + 0.5*(nb1[2j]+nb1[2j+1])
        const int p = wave;
        float acc = 0.0f;
        for (int s = 0; s < NS; ++s) {
            const int j = p * 16 + s;
            if (mask0_l[j]) {
                const int rel = rel1_l[j];
                const float ev1p = Rl[rel * DIM + lane] +
                    0.5f * (nb1[(2 * j) * DIM + lane] + nb1[(2 * j + 1) * DIM + lane]);
                acc += ev1p;
            }
        }
        sum1p[p][lane] = acc;
    } else {
        // masked sum of ORIGINAL ev1[j] = R[rel1[j]]; plus entity row
        const int p = wave - 2;
        float acc = 0.0f;
        for (int s = 0; s < NS; ++s) {
            const int j = p * 16 + s;
            if (mask0_l[j]) acc += Rl[rel1_l[j] * DIM + lane];
        }
        sum1[p][lane] = acc;
        const int e = entity_pairs[b * 2 + p];
        ent0[p][lane] = entity_emb[(long long)e * DIM + lane];
    }
    __syncthreads();

    // ---- final combine + score (wave 0) ----
    if (wave == 0) {
        int c00 = 0, c01 = 0;
        for (int s = 0; s < NS; ++s) { c00 += mask0_l[s]; c01 += mask0_l[16 + s]; }
        const float i0 = 1.0f / (float)max(c00, 1);
        const float i1 = 1.0f / (float)max(c01, 1);

        const int   r0  = relations[b];
        const float ev0 = Rl[r0 * DIM + lane];

        // iteration 0, hop 0 (uses original ev1 sums)
        const float n00 = ent0[0][lane] + sum1[0][lane] * i0;
        const float n01 = ent0[1][lane] + sum1[1][lane] * i1;
        const float ev0a = ev0 + 0.5f * (n00 + n01);

        // iteration 1, hop 0 (uses updated ev1' sums)
        const float n10 = ent0[0][lane] + sum1p[0][lane] * i0;
        const float n11 = ent0[1][lane] + sum1p[1][lane] * i1;
        const float ev0b = ev0a + 0.5f * (n10 + n11);

        float v = ev0b * scorer_w[lane];
        #pragma unroll
        for (int off = 32; off > 0; off >>= 1) v += __shfl_xor(v, off);
        if (lane == 0) out[b] = v + scorer_b[0];
    }
}

extern "C" void kernel_launch(void* const* d_in, const int* in_sizes, int n_in,
                              void* d_out, int out_size, void* d_ws, size_t ws_size,
                              hipStream_t stream) {
    const int*   relations    = (const int*)d_in[0];
    const int*   entity_pairs = (const int*)d_in[1];
    const int*   train_edges  = (const int*)d_in[2];
    const int*   entity2edges = (const int*)d_in[3];
    const int*   edge2entities= (const int*)d_in[4];
    const int*   edge2relation= (const int*)d_in[5];
    const float* relation_emb = (const float*)d_in[6];
    const float* entity_emb   = (const float*)d_in[7];
    const float* scorer_w     = (const float*)d_in[8];
    const float* scorer_b     = (const float*)d_in[9];
    float* out = (float*)d_out;

    transmatch_kernel<<<BSZ, 256, 0, stream>>>(
        relations, entity_pairs, train_edges, entity2edges, edge2entities,
        edge2relation, relation_emb, entity_emb, scorer_w, scorer_b, out);
}

// Round 2
// 22.798 us; speedup vs baseline: 1.1936x; 1.1936x over previous
//
#include <hip/hip_runtime.h>

// TransMatch scalarized: score depends only on dot(·, w), so all D=64 vector
// algebra collapses to scalar gathers:
//   score = b + Rw[r0] + sum_p( EW[e_p] + i_p*rw0sum_p
//                               + 0.25*i_p*sum_{n in p} m0_j*(EW[node_n] + rwsum_n/cnt_n) )
// Rw[r] = dot(relation_emb[r], w); EW[e] = dot(entity_emb[e], w);
// rwsum_n = masked sum of Rw over node n's 16 edges. Verified algebraically
// against the round-1 kernel (absmax 0.0 vs reference).
//
// Pre-kernel packs edge2relation (2M int32, 8MB) to u8 (2MB) in d_ws so the
// ~1M random relation gathers per launch are L2-resident.

#define DIM 64
#define NS 16
#define NREL 16

__global__ void pack_rel_kernel(const int* __restrict__ e2r,
                                unsigned char* __restrict__ rel8, int n) {
    int i = (blockIdx.x * blockDim.x + threadIdx.x) * 4;
    if (i + 3 < n) {
        const int4 v = *reinterpret_cast<const int4*>(e2r + i);
        uchar4 p4;
        p4.x = (unsigned char)v.x; p4.y = (unsigned char)v.y;
        p4.z = (unsigned char)v.z; p4.w = (unsigned char)v.w;
        *reinterpret_cast<uchar4*>(rel8 + i) = p4;
    } else {
        for (; i < n; ++i) rel8[i] = (unsigned char)e2r[i];
    }
}

template <bool PACKED>
__global__ __launch_bounds__(256) void transmatch_main(
    const int* __restrict__ relations,       // (BS,)
    const int* __restrict__ entity_pairs,    // (BS,2)
    const int* __restrict__ train_edges,     // (BS,)
    const int* __restrict__ entity2edges,    // (N_ENT,16)
    const int* __restrict__ edge2entities,   // (N_EDGE,2)
    const int* __restrict__ edge2relation,   // (N_EDGE,)
    const float* __restrict__ relation_emb,  // (16,64)
    const float* __restrict__ entity_emb,    // (N_ENT,64)
    const float* __restrict__ scorer_w,      // (64,)
    const float* __restrict__ scorer_b,      // (1,)
    const unsigned char* __restrict__ rel8,  // (N_EDGE,) u8 (if PACKED)
    float* __restrict__ out)                 // (BS,)
{
    __shared__ float RwL[NREL];   // dot(R[r], w)
    __shared__ float wL[DIM];
    __shared__ int   node_l[64];
    __shared__ int   m0i[32];
    __shared__ float c0s[2];
    __shared__ float ews[2];
    __shared__ float rw0s[2];
    __shared__ float wavesum[4];

    const int b    = blockIdx.x;
    const int t    = threadIdx.x;
    const int lane = t & 63;
    const int wave = t >> 6;
    const int te   = train_edges[b];

    if (t < DIM) wL[t] = scorer_w[t];

    int rel1 = 0, m0 = 0;  // live across the barrier in wave-0 lanes<32
    if (wave == 0 && lane < 32) {
        // first hop: j = p*16 + s
        const int p    = lane >> 4;
        const int e    = entity_pairs[b * 2 + p];
        const int edge = entity2edges[e * NS + (lane & 15)];
        m0   = (edge != te) ? 1 : 0;
        rel1 = PACKED ? (int)rel8[edge] : edge2relation[edge];
        const int2 nn = reinterpret_cast<const int2*>(edge2entities)[edge];
        node_l[2 * lane]     = nn.x;
        node_l[2 * lane + 1] = nn.y;
        m0i[lane] = m0;
        int c = m0;
        c += __shfl_xor(c, 1); c += __shfl_xor(c, 2);
        c += __shfl_xor(c, 4); c += __shfl_xor(c, 8);
        if ((lane & 15) == 0) c0s[p] = (float)c;
    } else if (wave == 1) {
        // EW[e_p] = dot(entity_emb[e_p], w)  (32 lanes per pair entity)
        const int p  = lane >> 5;
        const int e  = entity_pairs[b * 2 + p];
        const int k  = lane & 31;
        const float2 ev = reinterpret_cast<const float2*>(entity_emb)[e * 32 + k];
        float v = ev.x * scorer_w[2 * k] + ev.y * scorer_w[2 * k + 1];
        v += __shfl_xor(v, 1); v += __shfl_xor(v, 2); v += __shfl_xor(v, 4);
        v += __shfl_xor(v, 8); v += __shfl_xor(v, 16);
        if (k == 0) ews[p] = v;
    } else if (wave == 2) {
        // Rw[r] = dot(R[r], w): r = lane>>2, seg = lane&3 covers 16 dims
        const int r = lane >> 2, seg = lane & 3;
        const float4* R4 = reinterpret_cast<const float4*>(relation_emb);
        const float4* W4 = reinterpret_cast<const float4*>(scorer_w);
        float v = 0.0f;
        #pragma unroll
        for (int k = 0; k < 4; ++k) {
            const float4 rr = R4[r * 16 + seg * 4 + k];
            const float4 ww = W4[seg * 4 + k];
            v = fmaf(rr.x, ww.x, v); v = fmaf(rr.y, ww.y, v);
            v = fmaf(rr.z, ww.z, v); v = fmaf(rr.w, ww.w, v);
        }
        v += __shfl_xor(v, 1); v += __shfl_xor(v, 2);
        if (seg == 0) RwL[r] = v;
    }
    __syncthreads();

    // finish first-hop masked Rw sum (needed RwL)
    if (wave == 0 && lane < 32) {
        float rv = m0 ? RwL[rel1] : 0.0f;
        rv += __shfl_xor(rv, 1); rv += __shfl_xor(rv, 2);
        rv += __shfl_xor(rv, 4); rv += __shfl_xor(rv, 8);
        if ((lane & 15) == 0) rw0s[lane >> 4] = rv;
    }

    // second hop: thread t -> node n = t>>2, edge-quad sq = t&3
    {
        const int n    = t >> 2;
        const int sq   = t & 3;
        const int node = node_l[n];

        const int4 ed = reinterpret_cast<const int4*>(entity2edges)[node * 4 + sq];
        int ee[4] = { ed.x, ed.y, ed.z, ed.w };
        int rr[4];
        #pragma unroll
        for (int k = 0; k < 4; ++k)
            rr[k] = PACKED ? (int)rel8[ee[k]] : edge2relation[ee[k]];

        // entity row segment: dims [sq*16, sq*16+16)
        const float4* E4  = reinterpret_cast<const float4*>(entity_emb);
        const float4* wL4 = reinterpret_cast<const float4*>(wL);
        float dotp = 0.0f;
        #pragma unroll
        for (int k = 0; k < 4; ++k) {
            const float4 ev = E4[node * 16 + sq * 4 + k];
            const float4 ww = wL4[sq * 4 + k];
            dotp = fmaf(ev.x, ww.x, dotp); dotp = fmaf(ev.y, ww.y, dotp);
            dotp = fmaf(ev.z, ww.z, dotp); dotp = fmaf(ev.w, ww.w, dotp);
        }

        int cnt = 0; float rws = 0.0f;
        #pragma unroll
        for (int k = 0; k < 4; ++k) {
            if (ee[k] != te) { cnt++; rws += RwL[rr[k]]; }
        }

        // reduce over the node's 4 threads
        dotp += __shfl_xor(dotp, 1); dotp += __shfl_xor(dotp, 2);
        rws  += __shfl_xor(rws, 1);  rws  += __shfl_xor(rws, 2);
        cnt  += __shfl_xor(cnt, 1);  cnt  += __shfl_xor(cnt, 2);

        float v = 0.0f;
        if (sq == 0 && m0i[n >> 1])
            v = dotp + rws / (float)max(cnt, 1);

        // sum the wave's 16 nodes (sq!=0 lanes contribute 0)
        v += __shfl_xor(v, 4);  v += __shfl_xor(v, 8);
        v += __shfl_xor(v, 16); v += __shfl_xor(v, 32);
        if (lane == 0) wavesum[wave] = v;
    }
    __syncthreads();

    if (t == 0) {
        const float i0 = 1.0f / fmaxf(c0s[0], 1.0f);
        const float i1 = 1.0f / fmaxf(c0s[1], 1.0f);
        const float S0 = wavesum[0] + wavesum[1];  // pair 0 = nodes 0..31
        const float S1 = wavesum[2] + wavesum[3];  // pair 1 = nodes 32..63
        const int   r0 = relations[b];
        out[b] = scorer_b[0] + RwL[r0]
               + ews[0] + i0 * rw0s[0] + 0.25f * i0 * S0
               + ews[1] + i1 * rw0s[1] + 0.25f * i1 * S1;
    }
}

extern "C" void kernel_launch(void* const* d_in, const int* in_sizes, int n_in,
                              void* d_out, int out_size, void* d_ws, size_t ws_size,
                              hipStream_t stream) {
    const int*   relations     = (const int*)d_in[0];
    const int*   entity_pairs  = (const int*)d_in[1];
    const int*   train_edges   = (const int*)d_in[2];
    const int*   entity2edges  = (const int*)d_in[3];
    const int*   edge2entities = (const int*)d_in[4];
    const int*   edge2relation = (const int*)d_in[5];
    const float* relation_emb  = (const float*)d_in[6];
    const float* entity_emb    = (const float*)d_in[7];
    const float* scorer_w      = (const float*)d_in[8];
    const float* scorer_b      = (const float*)d_in[9];
    float* out = (float*)d_out;

    const int bs     = in_sizes[0];
    const int n_edge = in_sizes[5];

    if (ws_size >= (size_t)n_edge) {
        unsigned char* rel8 = (unsigned char*)d_ws;
        const int pack_blocks = (n_edge + 1023) / 1024;  // 4 edges/thread, 256 thr
        pack_rel_kernel<<<pack_blocks, 256, 0, stream>>>(edge2relation, rel8, n_edge);
        transmatch_main<true><<<bs, 256, 0, stream>>>(
            relations, entity_pairs, train_edges, entity2edges, edge2entities,
            edge2relation, relation_emb, entity_emb, scorer_w, scorer_b, rel8, out);
    } else {
        transmatch_main<false><<<bs, 256, 0, stream>>>(
            relations, entity_pairs, train_edges, entity2edges, edge2entities,
            edge2relation, relation_emb, entity_emb, scorer_w, scorer_b, nullptr, out);
    }
}

// Round 3
// 21.322 us; speedup vs baseline: 1.2762x; 1.0692x over previous
//
#include <hip/hip_runtime.h>

// TransMatch scalarized (see R2): score collapses to scalar gathers.
//   score = b + Rw[r0] + sum_p( EW[e_p] + i_p*rw0sum_p
//                               + 0.25*i_p*sum_{n in p} m0_j*(EW[node_n] + rwsum_n/cnt_n) )
// R3 change: occupancy attack. 512-thread blocks (8 waves) -> 8192 waves total
// = 32 waves/CU (hardware max), one thread per (node, edge-PAIR) in hop 2
// (halved per-thread serial chain). __launch_bounds__(512,8) caps VGPR at 64.

#define DIM 64
#define NS 16
#define NREL 16

__global__ void pack_rel_kernel(const int* __restrict__ e2r,
                                unsigned char* __restrict__ rel8, int n) {
    int i = (blockIdx.x * blockDim.x + threadIdx.x) * 4;
    if (i + 3 < n) {
        const int4 v = *reinterpret_cast<const int4*>(e2r + i);
        uchar4 p4;
        p4.x = (unsigned char)v.x; p4.y = (unsigned char)v.y;
        p4.z = (unsigned char)v.z; p4.w = (unsigned char)v.w;
        *reinterpret_cast<uchar4*>(rel8 + i) = p4;
    } else {
        for (; i < n; ++i) rel8[i] = (unsigned char)e2r[i];
    }
}

template <bool PACKED>
__global__ __launch_bounds__(512, 8) void transmatch_main(
    const int* __restrict__ relations,       // (BS,)
    const int* __restrict__ entity_pairs,    // (BS,2)
    const int* __restrict__ train_edges,     // (BS,)
    const int* __restrict__ entity2edges,    // (N_ENT,16)
    const int* __restrict__ edge2entities,   // (N_EDGE,2)
    const int* __restrict__ edge2relation,   // (N_EDGE,)
    const float* __restrict__ relation_emb,  // (16,64)
    const float* __restrict__ entity_emb,    // (N_ENT,64)
    const float* __restrict__ scorer_w,      // (64,)
    const float* __restrict__ scorer_b,      // (1,)
    const unsigned char* __restrict__ rel8,  // (N_EDGE,) u8 (if PACKED)
    float* __restrict__ out)                 // (BS,)
{
    __shared__ float RwL[NREL];   // dot(R[r], w)
    __shared__ float wL[DIM];
    __shared__ int   node_l[64];
    __shared__ int   m0i[32];
    __shared__ float c0s[2];
    __shared__ float ews[2];
    __shared__ float rw0s[2];
    __shared__ float wavesum[8];

    const int b    = blockIdx.x;
    const int t    = threadIdx.x;
    const int lane = t & 63;
    const int wave = t >> 6;
    const int te   = train_edges[b];

    if (t < DIM) wL[t] = scorer_w[t];

    int rel1 = 0, m0 = 0;  // live across the barrier in wave-0 lanes<32
    if (wave == 0 && lane < 32) {
        // first hop: j = p*16 + s
        const int p    = lane >> 4;
        const int e    = entity_pairs[b * 2 + p];
        const int edge = entity2edges[e * NS + (lane & 15)];
        m0   = (edge != te) ? 1 : 0;
        rel1 = PACKED ? (int)rel8[edge] : edge2relation[edge];
        const int2 nn = reinterpret_cast<const int2*>(edge2entities)[edge];
        reinterpret_cast<int2*>(node_l)[lane] = nn;
        m0i[lane] = m0;
        int c = m0;
        c += __shfl_xor(c, 1); c += __shfl_xor(c, 2);
        c += __shfl_xor(c, 4); c += __shfl_xor(c, 8);
        if ((lane & 15) == 0) c0s[p] = (float)c;
    } else if (wave == 1) {
        // EW[e_p] = dot(entity_emb[e_p], w)  (32 lanes per pair entity)
        const int p  = lane >> 5;
        const int e  = entity_pairs[b * 2 + p];
        const int k  = lane & 31;
        const float2 ev = reinterpret_cast<const float2*>(entity_emb)[e * 32 + k];
        float v = ev.x * scorer_w[2 * k] + ev.y * scorer_w[2 * k + 1];
        v += __shfl_xor(v, 1); v += __shfl_xor(v, 2); v += __shfl_xor(v, 4);
        v += __shfl_xor(v, 8); v += __shfl_xor(v, 16);
        if (k == 0) ews[p] = v;
    } else if (wave == 2) {
        // Rw[r] = dot(R[r], w): r = lane>>2, seg = lane&3 covers 16 dims
        const int r = lane >> 2, seg = lane & 3;
        const float4* R4 = reinterpret_cast<const float4*>(relation_emb);
        const float4* W4 = reinterpret_cast<const float4*>(scorer_w);
        float v = 0.0f;
        #pragma unroll
        for (int k = 0; k < 4; ++k) {
            const float4 rr = R4[r * 16 + seg * 4 + k];
            const float4 ww = W4[seg * 4 + k];
            v = fmaf(rr.x, ww.x, v); v = fmaf(rr.y, ww.y, v);
            v = fmaf(rr.z, ww.z, v); v = fmaf(rr.w, ww.w, v);
        }
        v += __shfl_xor(v, 1); v += __shfl_xor(v, 2);
        if (seg == 0) RwL[r] = v;
    }
    __syncthreads();

    // finish first-hop masked Rw sum (needed RwL)
    if (wave == 0 && lane < 32) {
        float rv = m0 ? RwL[rel1] : 0.0f;
        rv += __shfl_xor(rv, 1); rv += __shfl_xor(rv, 2);
        rv += __shfl_xor(rv, 4); rv += __shfl_xor(rv, 8);
        if ((lane & 15) == 0) rw0s[lane >> 4] = rv;
    }

    // second hop: thread t -> node n = t>>3, edge-pair h = t&7 (2 edges each)
    {
        const int n    = t >> 3;
        const int h    = t & 7;
        const int node = node_l[n];

        const int2 ed = reinterpret_cast<const int2*>(entity2edges)[node * 8 + h];
        const int ra = PACKED ? (int)rel8[ed.x] : edge2relation[ed.x];
        const int rb = PACKED ? (int)rel8[ed.y] : edge2relation[ed.y];

        // entity row segment: dims [h*8, h*8+8)  (8 lanes cover the 256B row)
        const float4* E4  = reinterpret_cast<const float4*>(entity_emb);
        const float4* wL4 = reinterpret_cast<const float4*>(wL);
        const float4 ev0 = E4[node * 16 + h * 2];
        const float4 ev1 = E4[node * 16 + h * 2 + 1];
        const float4 w0  = wL4[h * 2];
        const float4 w1  = wL4[h * 2 + 1];
        float dotp = 0.0f;
        dotp = fmaf(ev0.x, w0.x, dotp); dotp = fmaf(ev0.y, w0.y, dotp);
        dotp = fmaf(ev0.z, w0.z, dotp); dotp = fmaf(ev0.w, w0.w, dotp);
        dotp = fmaf(ev1.x, w1.x, dotp); dotp = fmaf(ev1.y, w1.y, dotp);
        dotp = fmaf(ev1.z, w1.z, dotp); dotp = fmaf(ev1.w, w1.w, dotp);

        int cnt = 0; float rws = 0.0f;
        if (ed.x != te) { cnt++; rws += RwL[ra]; }
        if (ed.y != te) { cnt++; rws += RwL[rb]; }

        // reduce over the node's 8 threads
        dotp += __shfl_xor(dotp, 1); dotp += __shfl_xor(dotp, 2); dotp += __shfl_xor(dotp, 4);
        rws  += __shfl_xor(rws, 1);  rws  += __shfl_xor(rws, 2);  rws  += __shfl_xor(rws, 4);
        cnt  += __shfl_xor(cnt, 1);  cnt  += __shfl_xor(cnt, 2);  cnt  += __shfl_xor(cnt, 4);

        float v = 0.0f;
        if (h == 0 && m0i[n >> 1])
            v = dotp + rws / (float)max(cnt, 1);

        // sum the wave's 8 nodes (h!=0 lanes contribute 0)
        v += __shfl_xor(v, 8); v += __shfl_xor(v, 16); v += __shfl_xor(v, 32);
        if (lane == 0) wavesum[wave] = v;
    }
    __syncthreads();

    if (t == 0) {
        const float i0 = 1.0f / fmaxf(c0s[0], 1.0f);
        const float i1 = 1.0f / fmaxf(c0s[1], 1.0f);
        // waves 0-3 cover nodes 0..31 (pair 0), waves 4-7 nodes 32..63 (pair 1)
        const float S0 = wavesum[0] + wavesum[1] + wavesum[2] + wavesum[3];
        const float S1 = wavesum[4] + wavesum[5] + wavesum[6] + wavesum[7];
        const int   r0 = relations[b];
        out[b] = scorer_b[0] + RwL[r0]
               + ews[0] + i0 * rw0s[0] + 0.25f * i0 * S0
               + ews[1] + i1 * rw0s[1] + 0.25f * i1 * S1;
    }
}

extern "C" void kernel_launch(void* const* d_in, const int* in_sizes, int n_in,
                              void* d_out, int out_size, void* d_ws, size_t ws_size,
                              hipStream_t stream) {
    const int*   relations     = (const int*)d_in[0];
    const int*   entity_pairs  = (const int*)d_in[1];
    const int*   train_edges   = (const int*)d_in[2];
    const int*   entity2edges  = (const int*)d_in[3];
    const int*   edge2entities = (const int*)d_in[4];
    const int*   edge2relation = (const int*)d_in[5];
    const float* relation_emb  = (const float*)d_in[6];
    const float* entity_emb    = (const float*)d_in[7];
    const float* scorer_w      = (const float*)d_in[8];
    const float* scorer_b      = (const float*)d_in[9];
    float* out = (float*)d_out;

    const int bs     = in_sizes[0];
    const int n_edge = in_sizes[5];

    if (ws_size >= (size_t)n_edge) {
        unsigned char* rel8 = (unsigned char*)d_ws;
        const int pack_blocks = (n_edge + 1023) / 1024;  // 4 edges/thread, 256 thr
        pack_rel_kernel<<<pack_blocks, 256, 0, stream>>>(edge2relation, rel8, n_edge);
        transmatch_main<true><<<bs, 512, 0, stream>>>(
            relations, entity_pairs, train_edges, entity2edges, edge2entities,
            edge2relation, relation_emb, entity_emb, scorer_w, scorer_b, rel8, out);
    } else {
        transmatch_main<false><<<bs, 512, 0, stream>>>(
            relations, entity_pairs, train_edges, entity2edges, edge2entities,
            edge2relation, relation_emb, entity_emb, scorer_w, scorer_b, nullptr, out);
    }
}